// Round 19
// baseline (135.825 us; speedup 1.0000x reference)
//
#include <hip/hip_runtime.h>

typedef unsigned short u16;
typedef unsigned int   u32;
typedef __bf16 bf16x2 __attribute__((ext_vector_type(2)));
typedef __bf16 bf16x8 __attribute__((ext_vector_type(8)));
typedef float  f32x4  __attribute__((ext_vector_type(4)));
typedef float  f32x16 __attribute__((ext_vector_type(16)));
typedef u32    u32x4  __attribute__((ext_vector_type(4)));

#define LOG2E 1.4426950408889634f

// fp32 -> bf16 round-to-nearest-even
__device__ __forceinline__ u16 f2bf(float f) {
  union { float f; u32 u; } v; v.f = f;
  u32 r = v.u + 0x7fffu + ((v.u >> 16) & 1u);
  return (u16)(r >> 16);
}

// pair-pack via __bf16 casts -> compiler selects v_cvt_pk_bf16_f32 (RNE)
__device__ __forceinline__ u32 pack2(float lo, float hi) {
  bf16x2 p = { (__bf16)lo, (__bf16)hi };
  return __builtin_bit_cast(u32, p);
}

#define GLOAD_LDS16(g, s) __builtin_amdgcn_global_load_lds( \
    (const __attribute__((address_space(1))) void*)(g),     \
    (__attribute__((address_space(3))) void*)(s), 16, 0, 0)

// ---------------- prep kernels ----------------

__global__ void k_convert(const float* __restrict__ in, u16* __restrict__ out) {
  int i = (blockIdx.x * 256 + threadIdx.x) * 8;
  float4 a = *(const float4*)(in + i);
  float4 b = *(const float4*)(in + i + 4);
  u16 o[8] = { f2bf(a.x), f2bf(a.y), f2bf(a.z), f2bf(a.w),
               f2bf(b.x), f2bf(b.y), f2bf(b.z), f2bf(b.w) };
  *(uint4*)(out + i) = *(const uint4*)o;
}

// z=0..2: W{q,k,v} -> WqkvT + z*1M elems ; z=3: Wo -> WoT.  WT[n][k] = W[k][n]
__global__ void k_transpose_w4(const float* __restrict__ Wq, const float* __restrict__ Wk,
                               const float* __restrict__ Wv, const float* __restrict__ Wo,
                               u16* __restrict__ WqkvT, u16* __restrict__ WoT) {
  const int z = blockIdx.z;
  const float* W = (z == 0) ? Wq : (z == 1) ? Wk : (z == 2) ? Wv : Wo;
  u16* WT = (z < 3) ? (WqkvT + ((size_t)z << 20)) : WoT;
  __shared__ float tile[64][65];
  const int t = threadIdx.x;
  const int n0 = blockIdx.x * 64, k0 = blockIdx.y * 64;
  const int r = t >> 4, c4 = (t & 15) * 4;
  #pragma unroll
  for (int rr = 0; rr < 64; rr += 16) {
    float4 v = *(const float4*)(W + (size_t)(k0 + r + rr) * 1024 + n0 + c4);
    tile[r + rr][c4]     = v.x; tile[r + rr][c4 + 1] = v.y;
    tile[r + rr][c4 + 2] = v.z; tile[r + rr][c4 + 3] = v.w;
  }
  __syncthreads();
  #pragma unroll
  for (int rr = 0; rr < 64; rr += 16) {
    u16 o[4] = { f2bf(tile[c4][r + rr]),     f2bf(tile[c4 + 1][r + rr]),
                 f2bf(tile[c4 + 2][r + rr]), f2bf(tile[c4 + 3][r + rr]) };
    *(ushort4*)(WT + (size_t)(n0 + r + rr) * 1024 + k0 + c4) = *(const ushort4*)o;
  }
}

// ---------------- GEMM: C[M][N] = A[M][K] * BT[N][K]^T ----------------
// m97 2-barrier structure, 128x128 tile, BK=32, 4 waves (2x2) -- R17 exact
// (R18's conflict-free LDS regressed: its per-lane staging source scattered
// adjacent lanes across 16 lines; TA coalescing needs adjacent-lane sharing).
// MODE 0: C bf16 row-major. MODE 1: C f32 + bias. MODE 2: QKV in
// fragment-ordered tile-major layout (R14), Q pre-scaled by LOG2E.

template<int MODE>
__global__ __launch_bounds__(256) void k_gemm_bt(
    const u16* __restrict__ A, const u16* __restrict__ BT,
    void* __restrict__ Cv, const float* __restrict__ bias,
    int M, int N, int K) {
  __shared__ u16 lA[2][128 * 32];
  __shared__ u16 lB[2][128 * 32];
  const int t = threadIdx.x;
  const int l = t & 63, w = t >> 6;
  const int bM = blockIdx.y * 128, bN = blockIdx.x * 128;
  const int wr = w >> 1, wc = w & 1;
  const int NT = K >> 5;

  f32x4 acc[4][4] = {};

  const int fA  = w * 512 + l * 8;
  const int r0  = fA >> 5;
  const int kc0 = fA & 31;

  auto stage = [&](int buf, int kt) {
    const u16* ga = A  + (size_t)(bM + r0) * K + kt * 32 + kc0;
    const u16* gb = BT + (size_t)(bN + r0) * K + kt * 32 + kc0;
    GLOAD_LDS16(ga, &lA[buf][w * 512]);
    GLOAD_LDS16(gb, &lB[buf][w * 512]);
    GLOAD_LDS16(ga + (size_t)64 * K, &lA[buf][2048 + w * 512]);
    GLOAD_LDS16(gb + (size_t)64 * K, &lB[buf][2048 + w * 512]);
  };

  stage(0, 0);
  __syncthreads();
  int buf = 0;
  for (int kt = 0; kt < NT; ++kt) {
    if (kt + 1 < NT) stage(buf ^ 1, kt + 1);
    bf16x8 af[4], bfr[4];
    #pragma unroll
    for (int m = 0; m < 4; ++m)
      af[m] = *(const bf16x8*)&lA[buf][(wr * 64 + m * 16 + (l & 15)) * 32 + (l >> 4) * 8];
    #pragma unroll
    for (int n = 0; n < 4; ++n)
      bfr[n] = *(const bf16x8*)&lB[buf][(wc * 64 + n * 16 + (l & 15)) * 32 + (l >> 4) * 8];
    #pragma unroll
    for (int m = 0; m < 4; ++m)
      #pragma unroll
      for (int n = 0; n < 4; ++n)
        acc[m][n] = __builtin_amdgcn_mfma_f32_16x16x32_bf16(af[m], bfr[n], acc[m][n], 0, 0, 0);
    __syncthreads();
    buf ^= 1;
  }

  #pragma unroll
  for (int m = 0; m < 4; ++m) {
    #pragma unroll
    for (int n = 0; n < 4; ++n) {
      const int row = bM + wr * 64 + m * 16 + (l >> 4) * 4;
      const int col = bN + wc * 64 + n * 16 + (l & 15);
      if (MODE == 1) {
        #pragma unroll
        for (int i = 0; i < 4; ++i)
          ((float*)Cv)[(size_t)(row + i) * N + col] = acc[m][n][i] + bias[col];
      } else if (MODE == 0) {
        #pragma unroll
        for (int i = 0; i < 4; ++i)
          ((u16*)Cv)[(size_t)(row + i) * N + col] = f2bf(acc[m][n][i]);
      } else {
        const int which = col >> 10;            // 0=Q 1=K 2=V
        const int h  = (col >> 6) & 15;
        const int d  = col & 63;
        const int bh = (row >> 11) * 16 + h;
        const int tile = (row & 2047) >> 5;
        const int tk = row & 31;                // multiple of 4
        u16* base = (u16*)Cv + (size_t)which * 4194304 + (size_t)bh * 131072 + tile * 2048;
        if (which == 2) {
          // V frag: rows i are consecutive toks -> same lane, j..j+3
          const int chunk = (d >> 5) * 2 + ((tk >> 4) & 1);
          const int lane  = (d & 31) + ((tk >> 3) & 1) * 32;
          const int j     = tk & 7;             // 0 or 4
          u16 o[4] = { f2bf(acc[m][n][0]), f2bf(acc[m][n][1]),
                       f2bf(acc[m][n][2]), f2bf(acc[m][n][3]) };
          *(ushort4*)(base + chunk * 512 + lane * 8 + j) = *(const ushort4*)o;
        } else {
          // Q/K frag: rows i are consecutive toks -> consecutive lanes
          const float qs = (which == 0) ? LOG2E : 1.0f;
          const int chunk = d >> 4;
          const int j     = d & 7;
          const int lane0 = tk + ((d >> 3) & 1) * 32;
          #pragma unroll
          for (int i = 0; i < 4; ++i)
            base[chunk * 512 + (lane0 + i) * 8 + j] = f2bf(acc[m][n][i] * qs);
        }
      }
    }
  }
}

// ---------------- flash attention (causal, no scale) ----------------
// R7 geometry: 1024 blocks x 4 waves, block owns (bh, pair {j,63-j}) =
// uniform 65 tiles; waves split concat k-range; 4-slot LDS merge at end.
// No-max softmax (R12), prescaled Q + permlane P-exchange (R13),
// fragment-ordered K/V/Q tiles (R14), split QK chains (R17). NEW (R19):
// K-tile REGISTER PREFETCH (A/B rotation) -- the K fragment load was the
// exposed head (~200cy L2) of every tile's serial chain; prefetching one
// tile ahead hides it under the previous tile's exp/pack/PV. +16 VGPR
// (~88), below any occupancy cliff (VGPR pool 2048/88 = 23 waves/CU).

__global__ __launch_bounds__(256, 4) void k_attn(
    const u16* __restrict__ qt_, const u16* __restrict__ kt_,
    const u16* __restrict__ vt_, u16* __restrict__ ctx) {
  __shared__ float obuf[4][32][64];   // [slot][q][d]
  __shared__ float lbuf[4][32];
  __shared__ float rbuf[32];

  const int t = threadIdx.x;
  const int l = t & 63, w = t >> 6;
  const int hi = l >> 5, ln = l & 31;
  const int bidx = blockIdx.x;
  const int x = bidx & 7;                    // XCD slot
  const int bh = x * 4 + ((bidx >> 3) & 3);  // 4 heads per XCD (KV L2-resident)
  const int j = bidx >> 5;                   // 0..31
  const int bb = bh >> 4, h = bh & 15;
  const size_t tokbase = (size_t)bb * 2048;
  const size_t hplane = (size_t)bh * 131072;

  const int B  = 64 - j;                     // boundary in concat space
  const int s0 = (65 * w) >> 2, s1 = (65 * (w + 1)) >> 2;
  const int l8 = l * 8;                      // fragment element offset

  f32x16 oa = {}, ob = {};
  float lh = 0.f;

  auto loadK = [&](bf16x8 (&kf)[4], const u16* kb) {
    #pragma unroll
    for (int ds = 0; ds < 4; ++ds)
      kf[ds] = *(const bf16x8*)(kb + ds * 512 + l8);
  };

  auto process = [&](const bf16x8 (&kf)[4], const u16* vb, const bf16x8 (&qf)[4],
                     bool diag) {
    // two independent 2-deep QK chains (R17); K already in registers (R19)
    f32x16 sca = {}, scb = {};
    sca = __builtin_amdgcn_mfma_f32_32x32x16_bf16(kf[0], qf[0], sca, 0, 0, 0);
    scb = __builtin_amdgcn_mfma_f32_32x32x16_bf16(kf[2], qf[2], scb, 0, 0, 0);
    sca = __builtin_amdgcn_mfma_f32_32x32x16_bf16(kf[1], qf[1], sca, 0, 0, 0);
    scb = __builtin_amdgcn_mfma_f32_32x32x16_bf16(kf[3], qf[3], scb, 0, 0, 0);

    // V fragments issued early: exp/pack below hides the latency
    bf16x8 v00 = *(const bf16x8*)(vb + l8);
    bf16x8 v01 = *(const bf16x8*)(vb + 512 + l8);
    bf16x8 v10 = *(const bf16x8*)(vb + 1024 + l8);
    bf16x8 v11 = *(const bf16x8*)(vb + 1536 + l8);

    if (diag) {
      #pragma unroll
      for (int r = 0; r < 16; ++r) {
        const int kloc = (r & 3) + 8 * (r >> 2) + 4 * hi;
        if (kloc > ln) sca[r] = -__builtin_inff();
      }
    }

    // no-max softmax; Q pre-scaled by log2e -> p = exp2(sca+scb) directly
    float ph[16];
    #pragma unroll
    for (int r = 0; r < 16; ++r) ph[r] = exp2f(sca[r] + scb[r]);
    float b0 = ph[0] + ph[1],   b1 = ph[2] + ph[3];
    float b2 = ph[4] + ph[5],   b3 = ph[6] + ph[7];
    float b4 = ph[8] + ph[9],   b5 = ph[10] + ph[11];
    float b6 = ph[12] + ph[13], b7 = ph[14] + ph[15];
    lh += ((b0 + b1) + (b2 + b3)) + ((b4 + b5) + (b6 + b7));

    u32 c0 = pack2(ph[0],  ph[1]),  c1 = pack2(ph[2],  ph[3]);
    u32 c2 = pack2(ph[4],  ph[5]),  c3 = pack2(ph[6],  ph[7]);
    u32 c4 = pack2(ph[8],  ph[9]),  c5 = pack2(ph[10], ph[11]);
    u32 c6 = pack2(ph[12], ph[13]), c7 = pack2(ph[14], ph[15]);
    // P-exchange via permlane32_swap (R13-verified vs R9 select tables)
    asm volatile("v_permlane32_swap_b32 %0, %1" : "+v"(c0), "+v"(c2));
    asm volatile("v_permlane32_swap_b32 %0, %1" : "+v"(c1), "+v"(c3));
    asm volatile("v_permlane32_swap_b32 %0, %1" : "+v"(c4), "+v"(c6));
    asm volatile("v_permlane32_swap_b32 %0, %1" : "+v"(c5), "+v"(c7));
    u32x4 wa0 = { c0, c1, c2, c3 };
    u32x4 wa1 = { c4, c5, c6, c7 };
    bf16x8 pa0 = __builtin_bit_cast(bf16x8, wa0);
    bf16x8 pa1 = __builtin_bit_cast(bf16x8, wa1);

    oa = __builtin_amdgcn_mfma_f32_32x32x16_bf16(pa0, v00, oa, 0, 0, 0);
    oa = __builtin_amdgcn_mfma_f32_32x32x16_bf16(pa1, v01, oa, 0, 0, 0);
    ob = __builtin_amdgcn_mfma_f32_32x32x16_bf16(pa0, v10, ob, 0, 0, 0);
    ob = __builtin_amdgcn_mfma_f32_32x32x16_bf16(pa1, v11, ob, 0, 0, 0);
  };

  auto stash = [&](int slot) {
    const float lr = lh + __shfl_xor(lh, 32);
    if (hi == 0) lbuf[slot][ln] = lr;
    #pragma unroll
    for (int r = 0; r < 16; ++r) {
      const int rm = (r & 3) + 8 * (r >> 2) + 4 * hi;
      obuf[slot][rm][ln]      = oa[r];
      obuf[slot][rm][ln + 32] = ob[r];
    }
  };

  auto runChain = [&](int qt, int k0, int k1) {
    if (k0 >= k1) return;
    bf16x8 qf[4];
    const u16* qq = qt_ + hplane + qt * 2048 + l8;
    #pragma unroll
    for (int ds = 0; ds < 4; ++ds) qf[ds] = *(const bf16x8*)(qq + ds * 512);
    const u16* kb = kt_ + hplane + k0 * 2048;
    const u16* vb = vt_ + hplane + k0 * 2048;

    bf16x8 kA[4], kB[4];
    loadK(kA, kb);
    for (int kt = k0; kt < k1; kt += 2) {
      const bool more1 = (kt + 1 < k1);
      if (more1) loadK(kB, kb + 2048);
      process(kA, vb, qf, kt == qt);
      if (more1) {
        if (kt + 2 < k1) loadK(kA, kb + 4096);
        process(kB, vb + 2048, qf, kt + 1 == qt);
      }
      kb += 4096; vb += 4096;
    }
  };

  // merge = plain addition (no max factors)
  auto mergeWrite = [&](int qt) {
    if (t < 32) {
      const int q = t;
      rbuf[q] = 1.0f / (lbuf[0][q] + lbuf[1][q] + lbuf[2][q] + lbuf[3][q]);
    }
    __syncthreads();
    u16* cb = ctx + (tokbase + qt * 32) * 1024 + h * 64;
    #pragma unroll
    for (int k2 = 0; k2 < 8; ++k2) {
      const int idx = t + k2 * 256;
      const int q = idx >> 6, d = idx & 63;
      const float v = obuf[0][q][d] + obuf[1][q][d] + obuf[2][q][d] + obuf[3][q][d];
      cb[(size_t)q * 1024 + d] = f2bf(v * rbuf[q]);
    }
  };

  // phase 0: chain qt=63-j, tiles [s0, min(s1,B))
  runChain(63 - j, s0, (s1 < B) ? s1 : B);
  stash(w);
  // reset, phase 1: chain qt=j, tiles [max(s0,B)-B, s1-B)
  oa = f32x16{}; ob = f32x16{}; lh = 0.f;
  runChain(j, ((s0 > B) ? s0 : B) - B, s1 - B);

  __syncthreads();
  mergeWrite(63 - j);          // merge chain-0 partials, write q-tile 63-j
  __syncthreads();             // slots free to overwrite
  stash(w);                    // chain-1 partials
  __syncthreads();
  mergeWrite(j);
}

// ---------------- launch ----------------

extern "C" void kernel_launch(void* const* d_in, const int* in_sizes, int n_in,
                              void* d_out, int out_size, void* d_ws, size_t ws_size,
                              hipStream_t stream) {
  const float* x  = (const float*)d_in[0];
  const float* Wq = (const float*)d_in[1];
  const float* Wk = (const float*)d_in[2];
  const float* Wv = (const float*)d_in[3];
  const float* Wo = (const float*)d_in[4];
  const float* bo = (const float*)d_in[5];
  float* out = (float*)d_out;
  char* ws = (char*)d_ws;

  // ws layout (bytes): [0,8M) xb; [8M,14M) WqkvT; [14M,16M) WoT;
  // [16M,40M) Qt/Kt/Vt fragment-ordered tile-major (8MB each); [40M,48M) ctx
  u16* xb    = (u16*)(ws);
  u16* WqkvT = (u16*)(ws + (8u  << 20));
  u16* WoT   = (u16*)(ws + (14u << 20));
  u16* Qt    = (u16*)(ws + (16u << 20));
  u16* Kt    = (u16*)(ws + (24u << 20));
  u16* Vt    = (u16*)(ws + (32u << 20));
  u16* ctxb  = (u16*)(ws + (40u << 20));

  k_convert<<<2048, 256, 0, stream>>>(x, xb);
  k_transpose_w4<<<dim3(16, 16, 4), 256, 0, stream>>>(Wq, Wk, Wv, Wo, WqkvT, WoT);

  // QKV = xb @ WqkvT^T, written straight into fragment-ordered Qt/Kt/Vt
  k_gemm_bt<2><<<dim3(24, 32), 256, 0, stream>>>(xb, WqkvT, Qt, nullptr, 4096, 3072, 1024);
  // causal MHA -> ctx [4096][1024] bf16
  k_attn<<<1024, 256, 0, stream>>>(Qt, Kt, Vt, ctxb);
  // out = ctx @ WoT^T + bo : fp32
  k_gemm_bt<1><<<dim3(8, 32), 256, 0, stream>>>(ctxb, WoT, out, bo, 4096, 1024, 1024);
}

// Round 20
// 106.932 us; speedup vs baseline: 1.2702x; 1.2702x over previous
//
#include <hip/hip_runtime.h>

typedef unsigned short u16;
typedef unsigned int   u32;
typedef __bf16 bf16x2 __attribute__((ext_vector_type(2)));
typedef __bf16 bf16x8 __attribute__((ext_vector_type(8)));
typedef float  f32x4  __attribute__((ext_vector_type(4)));
typedef float  f32x16 __attribute__((ext_vector_type(16)));
typedef u32    u32x4  __attribute__((ext_vector_type(4)));

#define LOG2E 1.4426950408889634f

// fp32 -> bf16 round-to-nearest-even
__device__ __forceinline__ u16 f2bf(float f) {
  union { float f; u32 u; } v; v.f = f;
  u32 r = v.u + 0x7fffu + ((v.u >> 16) & 1u);
  return (u16)(r >> 16);
}

// pair-pack via __bf16 casts -> compiler selects v_cvt_pk_bf16_f32 (RNE)
__device__ __forceinline__ u32 pack2(float lo, float hi) {
  bf16x2 p = { (__bf16)lo, (__bf16)hi };
  return __builtin_bit_cast(u32, p);
}

#define GLOAD_LDS16(g, s) __builtin_amdgcn_global_load_lds( \
    (const __attribute__((address_space(1))) void*)(g),     \
    (__attribute__((address_space(3))) void*)(s), 16, 0, 0)

// ---------------- prep kernels ----------------

__global__ void k_convert(const float* __restrict__ in, u16* __restrict__ out) {
  int i = (blockIdx.x * 256 + threadIdx.x) * 8;
  float4 a = *(const float4*)(in + i);
  float4 b = *(const float4*)(in + i + 4);
  u16 o[8] = { f2bf(a.x), f2bf(a.y), f2bf(a.z), f2bf(a.w),
               f2bf(b.x), f2bf(b.y), f2bf(b.z), f2bf(b.w) };
  *(uint4*)(out + i) = *(const uint4*)o;
}

// z=0..2: W{q,k,v} -> WqkvT + z*1M elems ; z=3: Wo -> WoT.  WT[n][k] = W[k][n]
__global__ void k_transpose_w4(const float* __restrict__ Wq, const float* __restrict__ Wk,
                               const float* __restrict__ Wv, const float* __restrict__ Wo,
                               u16* __restrict__ WqkvT, u16* __restrict__ WoT) {
  const int z = blockIdx.z;
  const float* W = (z == 0) ? Wq : (z == 1) ? Wk : (z == 2) ? Wv : Wo;
  u16* WT = (z < 3) ? (WqkvT + ((size_t)z << 20)) : WoT;
  __shared__ float tile[64][65];
  const int t = threadIdx.x;
  const int n0 = blockIdx.x * 64, k0 = blockIdx.y * 64;
  const int r = t >> 4, c4 = (t & 15) * 4;
  #pragma unroll
  for (int rr = 0; rr < 64; rr += 16) {
    float4 v = *(const float4*)(W + (size_t)(k0 + r + rr) * 1024 + n0 + c4);
    tile[r + rr][c4]     = v.x; tile[r + rr][c4 + 1] = v.y;
    tile[r + rr][c4 + 2] = v.z; tile[r + rr][c4 + 3] = v.w;
  }
  __syncthreads();
  #pragma unroll
  for (int rr = 0; rr < 64; rr += 16) {
    u16 o[4] = { f2bf(tile[c4][r + rr]),     f2bf(tile[c4 + 1][r + rr]),
                 f2bf(tile[c4 + 2][r + rr]), f2bf(tile[c4 + 3][r + rr]) };
    *(ushort4*)(WT + (size_t)(n0 + r + rr) * 1024 + k0 + c4) = *(const ushort4*)o;
  }
}

// ---------------- GEMM: C[M][N] = A[M][K] * BT[N][K]^T ----------------
// MODE 0: C bf16 row-major. MODE 1: C f32 + bias. MODE 2: QKV in
// FRAGMENT-ORDERED tile-major layout (R14): per (bh, 32-tok tile), 2048
// elems as 4 chunks x 64 lanes x 8 elems so the attention wave loads each
// fragment as ONE contiguous 1KB access. Q pre-scaled by LOG2E.

template<int MODE>
__global__ __launch_bounds__(256) void k_gemm_bt(
    const u16* __restrict__ A, const u16* __restrict__ BT,
    void* __restrict__ Cv, const float* __restrict__ bias,
    int M, int N, int K) {
  __shared__ u16 lA[2][128 * 32];
  __shared__ u16 lB[2][128 * 32];
  const int t = threadIdx.x;
  const int l = t & 63, w = t >> 6;
  const int bM = blockIdx.y * 128, bN = blockIdx.x * 128;
  const int wr = w >> 1, wc = w & 1;
  const int NT = K >> 5;

  f32x4 acc[4][4] = {};

  const int fA  = w * 512 + l * 8;
  const int r0  = fA >> 5;
  const int kc0 = fA & 31;

  auto stage = [&](int buf, int kt) {
    const u16* ga = A  + (size_t)(bM + r0) * K + kt * 32 + kc0;
    const u16* gb = BT + (size_t)(bN + r0) * K + kt * 32 + kc0;
    GLOAD_LDS16(ga, &lA[buf][w * 512]);
    GLOAD_LDS16(gb, &lB[buf][w * 512]);
    GLOAD_LDS16(ga + (size_t)64 * K, &lA[buf][2048 + w * 512]);
    GLOAD_LDS16(gb + (size_t)64 * K, &lB[buf][2048 + w * 512]);
  };

  stage(0, 0);
  __syncthreads();
  int buf = 0;
  for (int kt = 0; kt < NT; ++kt) {
    if (kt + 1 < NT) stage(buf ^ 1, kt + 1);
    bf16x8 af[4], bfr[4];
    #pragma unroll
    for (int m = 0; m < 4; ++m)
      af[m] = *(const bf16x8*)&lA[buf][(wr * 64 + m * 16 + (l & 15)) * 32 + (l >> 4) * 8];
    #pragma unroll
    for (int n = 0; n < 4; ++n)
      bfr[n] = *(const bf16x8*)&lB[buf][(wc * 64 + n * 16 + (l & 15)) * 32 + (l >> 4) * 8];
    #pragma unroll
    for (int m = 0; m < 4; ++m)
      #pragma unroll
      for (int n = 0; n < 4; ++n)
        acc[m][n] = __builtin_amdgcn_mfma_f32_16x16x32_bf16(af[m], bfr[n], acc[m][n], 0, 0, 0);
    __syncthreads();
    buf ^= 1;
  }

  #pragma unroll
  for (int m = 0; m < 4; ++m) {
    #pragma unroll
    for (int n = 0; n < 4; ++n) {
      const int row = bM + wr * 64 + m * 16 + (l >> 4) * 4;
      const int col = bN + wc * 64 + n * 16 + (l & 15);
      if (MODE == 1) {
        #pragma unroll
        for (int i = 0; i < 4; ++i)
          ((float*)Cv)[(size_t)(row + i) * N + col] = acc[m][n][i] + bias[col];
      } else if (MODE == 0) {
        #pragma unroll
        for (int i = 0; i < 4; ++i)
          ((u16*)Cv)[(size_t)(row + i) * N + col] = f2bf(acc[m][n][i]);
      } else {
        const int which = col >> 10;            // 0=Q 1=K 2=V
        const int h  = (col >> 6) & 15;
        const int d  = col & 63;
        const int bh = (row >> 11) * 16 + h;
        const int tile = (row & 2047) >> 5;
        const int tk = row & 31;                // multiple of 4
        u16* base = (u16*)Cv + (size_t)which * 4194304 + (size_t)bh * 131072 + tile * 2048;
        if (which == 2) {
          // V frag: rows i are consecutive toks -> same lane, j..j+3
          const int chunk = (d >> 5) * 2 + ((tk >> 4) & 1);
          const int lane  = (d & 31) + ((tk >> 3) & 1) * 32;
          const int j     = tk & 7;             // 0 or 4
          u16 o[4] = { f2bf(acc[m][n][0]), f2bf(acc[m][n][1]),
                       f2bf(acc[m][n][2]), f2bf(acc[m][n][3]) };
          *(ushort4*)(base + chunk * 512 + lane * 8 + j) = *(const ushort4*)o;
        } else {
          // Q/K frag: rows i are consecutive toks -> consecutive lanes
          const float qs = (which == 0) ? LOG2E : 1.0f;
          const int chunk = d >> 4;
          const int j     = d & 7;
          const int lane0 = tk + ((d >> 3) & 1) * 32;
          #pragma unroll
          for (int i = 0; i < 4; ++i)
            base[chunk * 512 + (lane0 + i) * 8 + j] = f2bf(acc[m][n][i] * qs);
        }
      }
    }
  }
}

// ---------------- flash attention (causal, no scale) ----------------
// R7 geometry: 1024 blocks x 4 waves, block owns (bh, pair {j,63-j}) =
// uniform 65 tiles; waves split concat k-range; 4-slot LDS merge at end.
// No-max softmax (R12), prescaled Q + permlane P-exchange (R13),
// fragment-ordered K/V/Q tiles (R14): every load is ONE contiguous 1KB
// wave access. S^T via swapped mfma(K,Q) 32x32x16.
// [R20: exact restore of the best-measured configuration (R14, 106.8us).
//  Register budget note (R8/R10/R19 lessons): live state ~120 unified regs
//  -> 4 waves/SIMD max; any added double-buffer spills. Do not re-add.]

__global__ __launch_bounds__(256, 4) void k_attn(
    const u16* __restrict__ qt_, const u16* __restrict__ kt_,
    const u16* __restrict__ vt_, u16* __restrict__ ctx) {
  __shared__ float obuf[4][32][64];   // [slot][q][d]
  __shared__ float lbuf[4][32];
  __shared__ float rbuf[32];

  const int t = threadIdx.x;
  const int l = t & 63, w = t >> 6;
  const int hi = l >> 5, ln = l & 31;
  const int bidx = blockIdx.x;
  const int x = bidx & 7;                    // XCD slot
  const int bh = x * 4 + ((bidx >> 3) & 3);  // 4 heads per XCD (KV L2-resident)
  const int j = bidx >> 5;                   // 0..31
  const int bb = bh >> 4, h = bh & 15;
  const size_t tokbase = (size_t)bb * 2048;
  const size_t hplane = (size_t)bh * 131072;

  const int B  = 64 - j;                     // boundary in concat space
  const int s0 = (65 * w) >> 2, s1 = (65 * (w + 1)) >> 2;
  const int l8 = l * 8;                      // fragment element offset

  f32x16 oa = {}, ob = {};
  float lh = 0.f;

  auto process = [&](const u16* kb, const u16* vb, const bf16x8 (&qf)[4], bool diag) {
    bf16x8 kf[4];
    #pragma unroll
    for (int ds = 0; ds < 4; ++ds)
      kf[ds] = *(const bf16x8*)(kb + ds * 512 + l8);

    f32x16 sc = {};
    #pragma unroll
    for (int ds = 0; ds < 4; ++ds)
      sc = __builtin_amdgcn_mfma_f32_32x32x16_bf16(kf[ds], qf[ds], sc, 0, 0, 0);

    // V fragments issued early: exp/pack below hides the latency
    bf16x8 v00 = *(const bf16x8*)(vb + l8);
    bf16x8 v01 = *(const bf16x8*)(vb + 512 + l8);
    bf16x8 v10 = *(const bf16x8*)(vb + 1024 + l8);
    bf16x8 v11 = *(const bf16x8*)(vb + 1536 + l8);

    if (diag) {
      #pragma unroll
      for (int r = 0; r < 16; ++r) {
        const int kloc = (r & 3) + 8 * (r >> 2) + 4 * hi;
        if (kloc > ln) sc[r] = -__builtin_inff();
      }
    }

    // no-max softmax; Q pre-scaled by log2e -> p = exp2(sc) directly
    float ph[16];
    #pragma unroll
    for (int r = 0; r < 16; ++r) ph[r] = exp2f(sc[r]);
    float b0 = ph[0] + ph[1],   b1 = ph[2] + ph[3];
    float b2 = ph[4] + ph[5],   b3 = ph[6] + ph[7];
    float b4 = ph[8] + ph[9],   b5 = ph[10] + ph[11];
    float b6 = ph[12] + ph[13], b7 = ph[14] + ph[15];
    lh += ((b0 + b1) + (b2 + b3)) + ((b4 + b5) + (b6 + b7));

    u32 c0 = pack2(ph[0],  ph[1]),  c1 = pack2(ph[2],  ph[3]);
    u32 c2 = pack2(ph[4],  ph[5]),  c3 = pack2(ph[6],  ph[7]);
    u32 c4 = pack2(ph[8],  ph[9]),  c5 = pack2(ph[10], ph[11]);
    u32 c6 = pack2(ph[12], ph[13]), c7 = pack2(ph[14], ph[15]);
    // P-exchange via permlane32_swap (R13-verified vs R9 select tables)
    asm volatile("v_permlane32_swap_b32 %0, %1" : "+v"(c0), "+v"(c2));
    asm volatile("v_permlane32_swap_b32 %0, %1" : "+v"(c1), "+v"(c3));
    asm volatile("v_permlane32_swap_b32 %0, %1" : "+v"(c4), "+v"(c6));
    asm volatile("v_permlane32_swap_b32 %0, %1" : "+v"(c5), "+v"(c7));
    u32x4 wa0 = { c0, c1, c2, c3 };
    u32x4 wa1 = { c4, c5, c6, c7 };
    bf16x8 pa0 = __builtin_bit_cast(bf16x8, wa0);
    bf16x8 pa1 = __builtin_bit_cast(bf16x8, wa1);

    oa = __builtin_amdgcn_mfma_f32_32x32x16_bf16(pa0, v00, oa, 0, 0, 0);
    oa = __builtin_amdgcn_mfma_f32_32x32x16_bf16(pa1, v01, oa, 0, 0, 0);
    ob = __builtin_amdgcn_mfma_f32_32x32x16_bf16(pa0, v10, ob, 0, 0, 0);
    ob = __builtin_amdgcn_mfma_f32_32x32x16_bf16(pa1, v11, ob, 0, 0, 0);
  };

  auto stash = [&](int slot) {
    const float lr = lh + __shfl_xor(lh, 32);
    if (hi == 0) lbuf[slot][ln] = lr;
    #pragma unroll
    for (int r = 0; r < 16; ++r) {
      const int rm = (r & 3) + 8 * (r >> 2) + 4 * hi;
      obuf[slot][rm][ln]      = oa[r];
      obuf[slot][rm][ln + 32] = ob[r];
    }
  };

  auto runChain = [&](int qt, int k0, int k1) {
    if (k0 >= k1) return;
    bf16x8 qf[4];
    const u16* qq = qt_ + hplane + qt * 2048 + l8;
    #pragma unroll
    for (int ds = 0; ds < 4; ++ds) qf[ds] = *(const bf16x8*)(qq + ds * 512);
    const u16* kb = kt_ + hplane + k0 * 2048;
    const u16* vb = vt_ + hplane + k0 * 2048;
    for (int kt = k0; kt < k1; ++kt) {
      process(kb, vb, qf, kt == qt);
      kb += 2048; vb += 2048;
    }
  };

  // merge = plain addition (no max factors)
  auto mergeWrite = [&](int qt) {
    if (t < 32) {
      const int q = t;
      rbuf[q] = 1.0f / (lbuf[0][q] + lbuf[1][q] + lbuf[2][q] + lbuf[3][q]);
    }
    __syncthreads();
    u16* cb = ctx + (tokbase + qt * 32) * 1024 + h * 64;
    #pragma unroll
    for (int k2 = 0; k2 < 8; ++k2) {
      const int idx = t + k2 * 256;
      const int q = idx >> 6, d = idx & 63;
      const float v = obuf[0][q][d] + obuf[1][q][d] + obuf[2][q][d] + obuf[3][q][d];
      cb[(size_t)q * 1024 + d] = f2bf(v * rbuf[q]);
    }
  };

  // phase 0: chain qt=63-j, tiles [s0, min(s1,B))
  runChain(63 - j, s0, (s1 < B) ? s1 : B);
  stash(w);
  // reset, phase 1: chain qt=j, tiles [max(s0,B)-B, s1-B)
  oa = f32x16{}; ob = f32x16{}; lh = 0.f;
  runChain(j, ((s0 > B) ? s0 : B) - B, s1 - B);

  __syncthreads();
  mergeWrite(63 - j);          // merge chain-0 partials, write q-tile 63-j
  __syncthreads();             // slots free to overwrite
  stash(w);                    // chain-1 partials
  __syncthreads();
  mergeWrite(j);
}

// ---------------- launch ----------------

extern "C" void kernel_launch(void* const* d_in, const int* in_sizes, int n_in,
                              void* d_out, int out_size, void* d_ws, size_t ws_size,
                              hipStream_t stream) {
  const float* x  = (const float*)d_in[0];
  const float* Wq = (const float*)d_in[1];
  const float* Wk = (const float*)d_in[2];
  const float* Wv = (const float*)d_in[3];
  const float* Wo = (const float*)d_in[4];
  const float* bo = (const float*)d_in[5];
  float* out = (float*)d_out;
  char* ws = (char*)d_ws;

  // ws layout (bytes): [0,8M) xb; [8M,14M) WqkvT; [14M,16M) WoT;
  // [16M,40M) Qt/Kt/Vt fragment-ordered tile-major (8MB each); [40M,48M) ctx
  u16* xb    = (u16*)(ws);
  u16* WqkvT = (u16*)(ws + (8u  << 20));
  u16* WoT   = (u16*)(ws + (14u << 20));
  u16* Qt    = (u16*)(ws + (16u << 20));
  u16* Kt    = (u16*)(ws + (24u << 20));
  u16* Vt    = (u16*)(ws + (32u << 20));
  u16* ctxb  = (u16*)(ws + (40u << 20));

  k_convert<<<2048, 256, 0, stream>>>(x, xb);
  k_transpose_w4<<<dim3(16, 16, 4), 256, 0, stream>>>(Wq, Wk, Wv, Wo, WqkvT, WoT);

  // QKV = xb @ WqkvT^T, written straight into fragment-ordered Qt/Kt/Vt
  k_gemm_bt<2><<<dim3(24, 32), 256, 0, stream>>>(xb, WqkvT, Qt, nullptr, 4096, 3072, 1024);
  // causal MHA -> ctx [4096][1024] bf16
  k_attn<<<1024, 256, 0, stream>>>(Qt, Kt, Vt, ctxb);
  // out = ctx @ WoT^T + bo : fp32
  k_gemm_bt<1><<<dim3(8, 32), 256, 0, stream>>>(ctxb, WoT, out, bo, 4096, 1024, 1024);
}